// Round 1
// baseline (381.716 us; speedup 1.0000x reference)
//
#include <hip/hip_runtime.h>
#include <math.h>

#define S      512
#define BATCH  32
#define NDIAG  (2 * S - 1)   // 1023
#define LDSP   68            // padded LDS row stride (floats): 68*4 = 272 B, 16B-aligned

// ---------------------------------------------------------------------------
// Kernel 1: D[b,i,j] = |x_i|^2 + |y_j|^2 - 2<x_i,y_j>, stored anti-diagonally:
//   ws[b][p][i] with p = i + j   (so the DP kernel reads coalesced rows)
// One block = one 64x64 tile of (i,j); 256 threads, 4x4 register blocking.
// ---------------------------------------------------------------------------
__global__ __launch_bounds__(256) void pairdist_kernel(
    const float* __restrict__ X, const float* __restrict__ Y,
    float* __restrict__ Dd)
{
    const int b   = blockIdx.z;
    const int i0  = blockIdx.y * 64;
    const int j0  = blockIdx.x * 64;
    const int tid = threadIdx.x;

    __shared__ float XsT[64][LDSP];  // [k][i] transposed so a-frag is contiguous
    __shared__ float YsT[64][LDSP];  // [k][j]
    __shared__ float x2s[64], y2s[64];

    const float* Xb = X + ((size_t)b * S + i0) * 64;
    const float* Yb = Y + ((size_t)b * S + j0) * 64;

    // Load 64x64 fp32 tiles (16 elems/thread via float4) and transpose into LDS.
#pragma unroll
    for (int c = 0; c < 4; ++c) {
        int idx = c * 1024 + tid * 4;   // element index inside the 64x64 tile
        int row = idx >> 6;             // 0..63
        int k   = idx & 63;             // multiple of 4
        float4 vx = *(const float4*)(Xb + (size_t)row * 64 + k);
        float4 vy = *(const float4*)(Yb + (size_t)row * 64 + k);
        XsT[k + 0][row] = vx.x; XsT[k + 1][row] = vx.y;
        XsT[k + 2][row] = vx.z; XsT[k + 3][row] = vx.w;
        YsT[k + 0][row] = vy.x; YsT[k + 1][row] = vy.y;
        YsT[k + 2][row] = vy.z; YsT[k + 3][row] = vy.w;
    }
    __syncthreads();

    // Row norms (threads 0..63 -> x, 64..127 -> y).
    if (tid < 64) {
        float s = 0.f;
#pragma unroll 8
        for (int k = 0; k < 64; ++k) { float v = XsT[k][tid]; s = fmaf(v, v, s); }
        x2s[tid] = s;
    } else if (tid < 128) {
        int r = tid - 64;
        float s = 0.f;
#pragma unroll 8
        for (int k = 0; k < 64; ++k) { float v = YsT[k][r]; s = fmaf(v, v, s); }
        y2s[r] = s;
    }
    __syncthreads();

    const int tx = tid & 15;   // j-group
    const int ty = tid >> 4;   // i-group
    float acc[4][4] = {};
#pragma unroll 4
    for (int k = 0; k < 64; ++k) {
        float4 a  = *(const float4*)&XsT[k][ty * 4];
        float4 bb = *(const float4*)&YsT[k][tx * 4];
        float av[4] = {a.x, a.y, a.z, a.w};
        float bv[4] = {bb.x, bb.y, bb.z, bb.w};
#pragma unroll
        for (int r = 0; r < 4; ++r)
#pragma unroll
            for (int c = 0; c < 4; ++c)
                acc[r][c] = fmaf(av[r], bv[c], acc[r][c]);
    }

    float xr[4], yc[4];
#pragma unroll
    for (int r = 0; r < 4; ++r) xr[r] = x2s[ty * 4 + r];
#pragma unroll
    for (int c = 0; c < 4; ++c) yc[c] = y2s[tx * 4 + c];

    float* Db = Dd + (size_t)b * NDIAG * S;
#pragma unroll
    for (int r = 0; r < 4; ++r) {
        int gi = i0 + ty * 4 + r;
#pragma unroll
        for (int c = 0; c < 4; ++c) {
            int gj = j0 + tx * 4 + c;
            int p  = gi + gj;
            Db[(size_t)p * S + gi] = xr[r] + yc[c] - 2.0f * acc[r][c];
        }
    }
}

// ---------------------------------------------------------------------------
// Kernel 2: soft-DTW anti-diagonal wavefront DP. One block per batch,
// thread t owns row i = t. Three rotating diagonals in LDS, 1 barrier/diag.
// softmin(a,b,c) = m - ln(e^{m-a} + e^{m-b} + e^{m-c}),  m = min (gamma = 1).
// ---------------------------------------------------------------------------
__global__ __launch_bounds__(512) void softdtw_dp_kernel(
    const float* __restrict__ Dd, float* __restrict__ out)
{
    const int b = blockIdx.x;
    const int t = threadIdx.x;   // row index i

    __shared__ float buf[3][S];

    buf[0][t] = INFINITY;        // diag p-2
    buf[1][t] = INFINITY;        // diag p-1
    __syncthreads();

    const float* Db = Dd + (size_t)b * NDIAG * S;

    int i2 = 0, i1 = 1, i0 = 2;
    float dcur = Db[t];          // D row for p = 0 (only i=0 valid there)

    for (int p = 0; p < NDIAG; ++p) {
        // prefetch next diagonal's D row (overlaps compute + barrier)
        float dnext = (p + 1 < NDIAG) ? Db[(size_t)(p + 1) * S + t] : 0.f;

        int  j     = p - t;
        bool valid = (j >= 0) && (j < S);

        float dd = (t == 0) ? ((p == 0) ? 0.f : INFINITY) : buf[i2][t - 1];
        float up = (t == 0) ? INFINITY : buf[i1][t - 1];
        float lf = buf[i1][t];

        float m = fminf(dd, fminf(up, lf));
        float soft;
        if (m < INFINITY) {
            // exp(m - x) = 0 when x = inf, IEEE-safe
            float s = __expf(m - dd) + __expf(m - up) + __expf(m - lf);
            soft = m - __logf(s);
        } else {
            soft = INFINITY;
        }

        float val = valid ? (dcur + soft) : INFINITY;
        buf[i0][t] = val;
        __syncthreads();

        dcur = dnext;
        int tmp = i2; i2 = i1; i1 = i0; i0 = tmp;
    }

    if (t == S - 1) out[b] = buf[i1][S - 1];
}

// ---------------------------------------------------------------------------
extern "C" void kernel_launch(void* const* d_in, const int* in_sizes, int n_in,
                              void* d_out, int out_size, void* d_ws, size_t ws_size,
                              hipStream_t stream)
{
    const float* X = (const float*)d_in[0];
    const float* Y = (const float*)d_in[1];
    float* out = (float*)d_out;
    float* Dd  = (float*)d_ws;   // needs 32*1023*512*4 = ~64 MiB

    dim3 g1(S / 64, S / 64, BATCH);   // 8 x 8 x 32
    pairdist_kernel<<<g1, 256, 0, stream>>>(X, Y, Dd);

    softdtw_dp_kernel<<<BATCH, S, 0, stream>>>(Dd, out);
}